// Round 6
// baseline (305.008 us; speedup 1.0000x reference)
//
#include <hip/hip_runtime.h>

// GraphFilter B=16,T=64,F=64,N=128,E=2,K=4 — v11: fused streaming recurrence,
// S transposed IN REGISTERS by the load assignment (lane = n-pair, loop m):
// after the coalesced dwordx2 loads each lane holds a COLUMN of S, packs it
// bf16 and writes S^T rows directly in the v9-proven XOR-block LDS layout.
// No in-LDS transpose passes, no tr16. Raw LDS-only barriers (lgkmcnt flush,
// NO vmcnt drain) -> the next-slice S register prefetch stays in flight
// across barriers and drains under proj+mm (T14). 2 barriers per e-step.
// proj / mm / spill / emit / prep are r4-passing code verbatim.
// Recurrence per (b,e):  Q[t] = U2[t] + S^T[t]@U3[t-1]
//                        P[t] = U1[t] + S^T[t]@Q[t-1]
//                        Y[t] = U0[t] + S^T[t]@P[t-1]  (sum over e, + bias)

namespace {
constexpr int B = 16, T = 64, F = 64, N = 128, E = 2, K = 4;
constexpr int SSW = 136;   // S^T row stride (ushorts)
constexpr int SZW = 136;   // state row stride (ushorts)
constexpr int TC = 8;      // outputs per block
}

typedef short v8s __attribute__((ext_vector_type(8)));
typedef float v4f __attribute__((ext_vector_type(4)));

__device__ inline ushort f2bf(float f) {
  union { float f; uint u; } v; v.f = f;
  uint u = v.u;
  return (ushort)((u + 0x7fffu + ((u >> 16) & 1u)) >> 16);
}

__device__ inline uint pk2(float a, float b) {
  return (uint)f2bf(a) | ((uint)f2bf(b) << 16);
}

// LDS-ordering barrier that does NOT drain vmcnt (prefetch stays in flight).
#define LBAR() do { \
  asm volatile("s_waitcnt lgkmcnt(0)" ::: "memory"); \
  __builtin_amdgcn_s_barrier(); \
  __builtin_amdgcn_sched_barrier(0); \
} while (0)

// ---- prep (r4-proven, passed): x -> xT bf16 [n][f]; H -> Hb [e][k][o][f] ----
__device__ inline void tr64x128(const float* __restrict__ src,
                                ushort* __restrict__ dst, int dstride,
                                ushort* sh, int tid) {
  float4 r0[4], r1[4];
  #pragma unroll
  for (int it = 0; it < 4; ++it) {
    const int idx = tid + it * 256;
    const int m = idx >> 4, g = idx & 15;
    r0[it] = *(const float4*)(src + m * N + g * 8);
    r1[it] = *(const float4*)(src + m * N + g * 8 + 4);
  }
  #pragma unroll
  for (int it = 0; it < 4; ++it) {
    const int idx = tid + it * 256;
    const int m = idx >> 4, g = idx & 15;
    uint4 wv;
    wv.x = pk2(r0[it].x, r0[it].y); wv.y = pk2(r0[it].z, r0[it].w);
    wv.z = pk2(r1[it].x, r1[it].y); wv.w = pk2(r1[it].z, r1[it].w);
    *(uint4*)&sh[m * SSW + ((g ^ (m >> 3)) * 8)] = wv;
  }
  __syncthreads();
  const int bb = tid & 7, a = (tid >> 3) & 15, hh = tid >> 7;
  v8s rows[8];
  #pragma unroll
  for (int j = 0; j < 8; ++j)
    rows[j] = *(const v8s*)&sh[(8 * bb + j) * SSW + ((a ^ bb) * 8)];
  #pragma unroll
  for (int i = 0; i < 4; ++i) {
    const int e = 4 * hh + i;
    const int n = 8 * a + e;
    uint4 wv;
    wv.x = (uint)(ushort)rows[0][e] | ((uint)(ushort)rows[1][e] << 16);
    wv.y = (uint)(ushort)rows[2][e] | ((uint)(ushort)rows[3][e] << 16);
    wv.z = (uint)(ushort)rows[4][e] | ((uint)(ushort)rows[5][e] << 16);
    wv.w = (uint)(ushort)rows[6][e] | ((uint)(ushort)rows[7][e] << 16);
    *(uint4*)(dst + n * dstride + 8 * bb) = wv;
  }
}

__global__ __launch_bounds__(256) void gf_prep(
    const float* __restrict__ x, const float* __restrict__ H,
    ushort* __restrict__ xT, ushort* __restrict__ Hb) {
  __shared__ ushort sh[64 * SSW];
  const int bid = blockIdx.x;
  const int tid = threadIdx.x;
  if (bid < B * T) {
    tr64x128(x + (size_t)bid * F * N, xT + (size_t)bid * N * F, F, sh, tid);
  } else {
    const int hb = bid - B * T;
    const int d = (hb * 256 + tid) * 4;    // linear over [e][k][o][f]
    const int f = d & 63, o = (d >> 6) & 63, k = (d >> 12) & 3, e = (d >> 14) & 1;
    const float4 v = *(const float4*)(H + (((size_t)o * E + e) * K + k) * F + f);
    uint2 wv;
    wv.x = pk2(v.x, v.y);
    wv.y = pk2(v.z, v.w);
    *(uint2*)(Hb + d) = wv;
  }
}

// ---- fused chain ----
__global__ __launch_bounds__(256, 2) void gf_fused(
    const float* __restrict__ S, const ushort* __restrict__ xT,
    const ushort* __restrict__ Hb, const float* __restrict__ bias,
    float* __restrict__ y) {
  __shared__ __align__(16) ushort sST[128 * SSW];   // 34.8 KB: S^T [n][m], XOR-block
  __shared__ __align__(16) ushort sSt[6][16 * SZW]; // 26.1 KB: states e*3+{P,Q,U3}
  // o-split siblings (same b,chunk) pinned to the SAME XCD for S L2 locality
  const int g = blockIdx.x;
  const int xcd = g & 7, loc = g >> 3;
  const int os = loc & 3, unitL = loc >> 2;
  const int unit = xcd * 16 + unitL;         // (b, chunk)
  const int b = unit >> 3, chunk = unit & 7;
  const int t0 = chunk * TC;
  const int ob = os * 16;
  const int tid = threadIdx.x, w = tid >> 6, lane = tid & 63;
  const int l15 = lane & 15, q = lane >> 4;

  for (int i = tid; i < 6 * 16 * SZW; i += 256) ((ushort*)sSt)[i] = 0;

  v4f Yac[2];
  Yac[0][0] = 0.f; Yac[0][1] = 0.f; Yac[0][2] = 0.f; Yac[0][3] = 0.f;
  Yac[1] = Yac[0];

  const int tstart = (t0 == 0) ? 0 : t0 - 3;
  const int tS0 = (t0 == 0) ? 0 : t0 - 2;

  // S prefetch: lane owns columns n = 2*lane, 2*lane+1; wave w owns m in
  // [32w, 32w+32). Per-instruction the wave reads one contiguous 512B m-row.
  float2 pfS[32];
  {
    const float* Sg = S + (size_t)((b * T + tS0) * E + 0) * (N * N) +
                      (size_t)(32 * w) * N + 2 * lane;
    #pragma unroll
    for (int j = 0; j < 32; ++j) pfS[j] = *(const float2*)(Sg + j * N);
  }
  // current / next x fragments
  v8s xfc[2][2], xfn[2][2];
  {
    const ushort* xrow = xT + (size_t)(b * T + tstart) * (N * F);
    #pragma unroll
    for (int mt = 0; mt < 2; ++mt)
      #pragma unroll
      for (int fk = 0; fk < 2; ++fk)
        xfc[mt][fk] = *(const v8s*)(xrow + ((2 * w + mt) * 16 + l15) * F +
                                    fk * 32 + q * 8);
  }

  LBAR();   // sSt zero-fill visible

  for (int t = tstart; t < t0 + TC; ++t) {
    const bool staged = (t >= tS0);
    const bool emit = (t >= t0);

    // issue next-step x fragments (drain over this t-step)
    {
      const int tn = (t + 1 < t0 + TC) ? t + 1 : t;
      const ushort* xrow = xT + (size_t)(b * T + tn) * (N * F);
      #pragma unroll
      for (int mt = 0; mt < 2; ++mt)
        #pragma unroll
        for (int fk = 0; fk < 2; ++fk)
          xfn[mt][fk] = *(const v8s*)(xrow + ((2 * w + mt) * 16 + l15) * F +
                                      fk * 32 + q * 8);
    }

    #pragma unroll
    for (int e = 0; e < E; ++e) {
      if (staged) {
        // pack registers -> sST rows n=2*lane(+1), blocks 4w..4w+3, stored at
        // block^(n>>3) (v9 convention). Conflict-free: 8 lanes per bank-quad.
        #pragma unroll
        for (int r = 0; r < 2; ++r) {
          const int n = 2 * lane + r;
          const int nb = n >> 3;
          #pragma unroll
          for (int i = 0; i < 4; ++i) {
            const float2* p0 = &pfS[8 * i];
            uint4 wv;
            wv.x = r ? pk2(p0[0].y, p0[1].y) : pk2(p0[0].x, p0[1].x);
            wv.y = r ? pk2(p0[2].y, p0[3].y) : pk2(p0[2].x, p0[3].x);
            wv.z = r ? pk2(p0[4].y, p0[5].y) : pk2(p0[4].x, p0[5].x);
            wv.w = r ? pk2(p0[6].y, p0[7].y) : pk2(p0[6].x, p0[7].x);
            *(uint4*)&sST[n * SSW + (((4 * w + i) ^ nb) * 8)] = wv;
          }
        }
        // prefetch next staged slice (stays in flight across raw barriers)
        const int nt = (e == 0) ? t : t + 1;
        const int ne = e ^ 1;
        if (nt < t0 + TC) {
          const float* Sg = S + (size_t)((b * T + nt) * E + ne) * (N * N) +
                            (size_t)(32 * w) * N + 2 * lane;
          #pragma unroll
          for (int j = 0; j < 32; ++j) pfS[j] = *(const float2*)(Sg + j * N);
        }
      }
      LBAR();   // bar1: sST ready, prev spill visible

      // ---- proj: U0->Y, U1->Pn, U2->Qn, U3->U3n (r4 verbatim) ----
      v4f Pn[2], Qn[2], U3n[2];
      #pragma unroll
      for (int mt = 0; mt < 2; ++mt) {
        Pn[mt][0] = 0.f; Pn[mt][1] = 0.f; Pn[mt][2] = 0.f; Pn[mt][3] = 0.f;
        Qn[mt] = Pn[mt]; U3n[mt] = Pn[mt];
      }
      #pragma unroll
      for (int k = 0; k < 4; ++k) {
        if (k == 0 && !emit) continue;
        const ushort* hrow = Hb + ((size_t)((e * K + k) * 64) + ob + l15) * 64;
        v8s hf[2];
        hf[0] = *(const v8s*)(hrow + q * 8);
        hf[1] = *(const v8s*)(hrow + 32 + q * 8);
        v4f* tgt = (k == 0) ? Yac : (k == 1 ? Pn : (k == 2 ? Qn : U3n));
        #pragma unroll
        for (int fk = 0; fk < 2; ++fk)
          #pragma unroll
          for (int mt = 0; mt < 2; ++mt)
            tgt[mt] = __builtin_amdgcn_mfma_f32_16x16x32_bf16(
                xfc[mt][fk], hf[fk], tgt[mt], 0, 0, 0);
      }

      if (staged) {
        // ---- mm: Y += S^T@P; Pn += S^T@Q; Qn += S^T@U3 (r4 verbatim) ----
        __builtin_amdgcn_s_setprio(1);
        #pragma unroll
        for (int c = 0; c < 4; ++c) {
          const int p = ((4 * c + q) + 2 * l15) & 15;
          const int sbase = l15 * SZW + p * 8;
          const v8s bzP = *(const v8s*)&sSt[e * 3 + 0][sbase];
          const v8s bzQ = *(const v8s*)&sSt[e * 3 + 1][sbase];
          const v8s bzU = *(const v8s*)&sSt[e * 3 + 2][sbase];
          #pragma unroll
          for (int mt = 0; mt < 2; ++mt) {
            const int n = (2 * w + mt) * 16 + l15;
            const v8s af = *(const v8s*)&sST[n * SSW +
                                             ((((c << 2) | q) ^ (n >> 3)) * 8)];
            if (emit)
              Yac[mt] = __builtin_amdgcn_mfma_f32_16x16x32_bf16(
                  af, bzP, Yac[mt], 0, 0, 0);
            Pn[mt] = __builtin_amdgcn_mfma_f32_16x16x32_bf16(
                af, bzQ, Pn[mt], 0, 0, 0);
            Qn[mt] = __builtin_amdgcn_mfma_f32_16x16x32_bf16(
                af, bzU, Qn[mt], 0, 0, 0);
          }
        }
        __builtin_amdgcn_s_setprio(0);
      }
      LBAR();   // bar2: all LDS reads of sST/sSt done

      // ---- spill Pn,Qn,U3n -> sSt[e] (r4 verbatim) ----
      #pragma unroll
      for (int mt = 0; mt < 2; ++mt) {
        const int cc = (2 * w + mt) * 2 + (q >> 1), h = q & 1;
        const int p = (cc + 2 * l15) & 15;
        const int base = l15 * SZW + p * 8 + h * 4;
        uint2 wv;
        wv.x = pk2(Pn[mt][0], Pn[mt][1]); wv.y = pk2(Pn[mt][2], Pn[mt][3]);
        *(uint2*)&sSt[e * 3 + 0][base] = wv;
        wv.x = pk2(Qn[mt][0], Qn[mt][1]); wv.y = pk2(Qn[mt][2], Qn[mt][3]);
        *(uint2*)&sSt[e * 3 + 1][base] = wv;
        wv.x = pk2(U3n[mt][0], U3n[mt][1]); wv.y = pk2(U3n[mt][2], U3n[mt][3]);
        *(uint2*)&sSt[e * 3 + 2][base] = wv;
      }

      // ---- emit y after e==1 (r4 verbatim) ----
      if (e == 1 && emit) {
        float* yg = y + (size_t)(b * T + t) * (F * N);
        const float bv = bias[ob + l15];
        #pragma unroll
        for (int mt = 0; mt < 2; ++mt) {
          float4 v;
          v.x = Yac[mt][0] + bv; v.y = Yac[mt][1] + bv;
          v.z = Yac[mt][2] + bv; v.w = Yac[mt][3] + bv;
          *(float4*)(yg + (ob + l15) * N + (2 * w + mt) * 16 + q * 4) = v;
          Yac[mt][0] = 0.f; Yac[mt][1] = 0.f;
          Yac[mt][2] = 0.f; Yac[mt][3] = 0.f;
        }
      }
    }

    #pragma unroll
    for (int mt = 0; mt < 2; ++mt)
      #pragma unroll
      for (int fk = 0; fk < 2; ++fk)
        xfc[mt][fk] = xfn[mt][fk];
  }
}

extern "C" void kernel_launch(void* const* d_in, const int* in_sizes, int n_in,
                              void* d_out, int out_size, void* d_ws, size_t ws_size,
                              hipStream_t stream) {
  const float* x    = (const float*)d_in[0];
  const float* S    = (const float*)d_in[1];
  const float* H    = (const float*)d_in[2];
  const float* bias = (const float*)d_in[3];
  float* y = (float*)d_out;

  const size_t XTn = (size_t)B * T * N * F;   // 8.39M ushorts (16.8 MB)
  ushort* xT = (ushort*)d_ws;
  ushort* Hb = xT + XTn;                      // 32768 ushorts

  gf_prep <<<B * T + 32, 256, 0, stream>>>(x, H, xT, Hb);
  gf_fused<<<512,        256, 0, stream>>>(S, xT, Hb, bias, y);
}